// Round 10
// baseline (581.632 us; speedup 1.0000x reference)
//
#include <hip/hip_runtime.h>
#include <hip/hip_fp16.h>
#include <math.h>

#define N_NODES 100000
#define N_EDGES 1600000
#define N_ITEMS (N_EDGES + N_NODES)   // edges + self loops
#define F_IN 128
#define F_E 8
#define HC 64      // H*C (layer-1 output width)
#define NHEAD 4
#define NEG 0.2f
#define SCAN_BS 1024
#define SCAN_NB ((N_NODES + SCAN_BS - 1) / SCAN_BS)   // 98
#define MS_BLOCKS 1024
#define NEG_BIG (-3.0e38f)

union H2I { __half2 h; int i; };
typedef int v2i __attribute__((ext_vector_type(2)));
typedef int v4i __attribute__((ext_vector_type(4)));

__device__ __forceinline__ float4 h4_to_f4(v2i w) {
    H2I u0, u1; u0.i = w.x; u1.i = w.y;
    float2 a = __half22float2(u0.h), b = __half22float2(u1.h);
    return make_float4(a.x, a.y, b.x, b.y);
}
__device__ __forceinline__ float4 h8_lo(v4i r) {
    H2I h0, h1; h0.i = r.x; h1.i = r.y;
    float2 f0 = __half22float2(h0.h), f1 = __half22float2(h1.h);
    return make_float4(f0.x, f0.y, f1.x, f1.y);
}
__device__ __forceinline__ float4 h8_hi(v4i r) {
    H2I h2, h3; h2.i = r.z; h3.i = r.w;
    float2 f2 = __half22float2(h2.h), f3 = __half22float2(h3.h);
    return make_float4(f2.x, f2.y, f3.x, f3.y);
}

// partial sums of edge_attr columns + degree histogram (deg pre-zeroed via memsetAsync)
__global__ void mean_sum_kernel(const float* __restrict__ ea, const int* __restrict__ dst,
                                float* __restrict__ partials, unsigned* __restrict__ deg) {
    __shared__ float sh[4][8];
    int stride = gridDim.x * blockDim.x;
    float acc[8] = {0.f,0.f,0.f,0.f,0.f,0.f,0.f,0.f};
    for (int r = blockIdx.x * blockDim.x + threadIdx.x; r < N_EDGES; r += stride) {
        const float4* p = (const float4*)(ea + (size_t)r * 8);
        float4 a = p[0], b = p[1];
        acc[0] += a.x; acc[1] += a.y; acc[2] += a.z; acc[3] += a.w;
        acc[4] += b.x; acc[5] += b.y; acc[6] += b.z; acc[7] += b.w;
        atomicAdd(&deg[dst[r]], 1u);
    }
    int wid  = threadIdx.x >> 6;
    int lane = threadIdx.x & 63;
#pragma unroll
    for (int k = 0; k < 8; k++) {
        float v = acc[k];
        for (int off = 32; off; off >>= 1) v += __shfl_down(v, off);
        if (lane == 0) sh[wid][k] = v;
    }
    __syncthreads();
    if (threadIdx.x < 8) {
        float s = sh[0][threadIdx.x] + sh[1][threadIdx.x] + sh[2][threadIdx.x] + sh[3][threadIdx.x];
        partials[blockIdx.x * 8 + threadIdx.x] = s;
    }
}

__global__ void reduce_sum8(const float* __restrict__ partials, float* __restrict__ sum8) {
    int lane = threadIdx.x;       // 64 threads
    int c = lane & 7, g = lane >> 3;
    float s = 0.f;
    for (int b = g; b < MS_BLOCKS; b += 8) s += partials[b * 8 + c];
    s += __shfl_xor(s, 8);
    s += __shfl_xor(s, 16);
    s += __shfl_xor(s, 32);
    if (lane < 8) sum8[lane] = s;
}

// inclusive block scan of (deg+1) via shfl wave-scans
__global__ void scan1(const unsigned* __restrict__ deg, unsigned* __restrict__ local_inc,
                      unsigned* __restrict__ bsum) {
    __shared__ unsigned wsum[16];
    int i = blockIdx.x * SCAN_BS + threadIdx.x;
    int lane = threadIdx.x & 63;
    int wid  = threadIdx.x >> 6;          // 0..15
    unsigned v = (i < N_NODES) ? (deg[i] + 1u) : 0u;   // +1 = self loop
    unsigned sc = v;
#pragma unroll
    for (int off = 1; off < 64; off <<= 1) {
        unsigned t = __shfl_up(sc, off);
        if (lane >= off) sc += t;
    }
    if (lane == 63) wsum[wid] = sc;
    __syncthreads();
    if (threadIdx.x < 16) {
        unsigned w = wsum[threadIdx.x];
#pragma unroll
        for (int off = 1; off < 16; off <<= 1) {
            unsigned t = __shfl_up(w, off);
            if ((int)threadIdx.x >= off) w += t;
        }
        wsum[threadIdx.x] = w;
    }
    __syncthreads();
    unsigned base = wid ? wsum[wid - 1] : 0u;
    sc += base;
    if (i < N_NODES) local_inc[i] = sc;
    if (threadIdx.x == SCAN_BS - 1) bsum[blockIdx.x] = sc;
}

__global__ void scan2(unsigned* __restrict__ bsum) {
    __shared__ unsigned tmp[128];
    int t = threadIdx.x;
    unsigned v = (t < SCAN_NB) ? bsum[t] : 0u;
    tmp[t] = v;
    __syncthreads();
    for (int off = 1; off < 128; off <<= 1) {
        unsigned add = (t >= off) ? tmp[t - off] : 0u;
        __syncthreads();
        tmp[t] += add;
        __syncthreads();
    }
    if (t < SCAN_NB) bsum[t] = tmp[t] - v;   // exclusive
}

__global__ void scan3(const unsigned* __restrict__ local_inc, const unsigned* __restrict__ deg,
                      const unsigned* __restrict__ bsum,
                      unsigned* __restrict__ row_start, unsigned* __restrict__ next) {
    int i = blockIdx.x * blockDim.x + threadIdx.x;
    if (i >= N_NODES) return;
    unsigned v = local_inc[i] - (deg[i] + 1u) + bsum[i / SCAN_BS];
    row_start[i] = v;
    next[i] = v;
}

// scatter edges (+ self loops) into destination-sorted order; sea fp16; see2 scalar
__global__ void scatter_kernel(const int* __restrict__ src, const int* __restrict__ dst,
                               const float* __restrict__ ea, const float* __restrict__ sum8,
                               const float* __restrict__ We2,
                               unsigned* __restrict__ next,
                               int* __restrict__ sorted_src, __half* __restrict__ seah,
                               float* __restrict__ see2) {
    int item = blockIdx.x * blockDim.x + threadIdx.x;
    if (item >= N_ITEMS) return;
    int s, d;
    float4 a, b;
    if (item < N_EDGES) {
        s = src[item]; d = dst[item];
        const float4* p = (const float4*)(ea + (size_t)item * 8);
        a = p[0]; b = p[1];
    } else {
        s = d = item - N_EDGES;
        const float inv = 1.0f / N_EDGES;
        a = make_float4(sum8[0]*inv, sum8[1]*inv, sum8[2]*inv, sum8[3]*inv);
        b = make_float4(sum8[4]*inv, sum8[5]*inv, sum8[6]*inv, sum8[7]*inv);
    }
    float ee2 = a.x*We2[0] + a.y*We2[1] + a.z*We2[2] + a.w*We2[3]
              + b.x*We2[4] + b.y*We2[5] + b.z*We2[6] + b.w*We2[7];
    unsigned pos = atomicAdd(&next[d], 1u);
    sorted_src[pos] = s;
    see2[pos] = ee2;
    H2I p0, p1, p2, p3;
    p0.h = __floats2half2_rn(a.x, a.y);
    p1.h = __floats2half2_rn(a.z, a.w);
    p2.h = __floats2half2_rn(b.x, b.y);
    p3.h = __floats2half2_rn(b.z, b.w);
    *(int4*)(seah + (size_t)pos * 8) = make_int4(p0.i, p1.i, p2.i, p3.i);
}

// xl = x@Wl + bl ; xr = x@Wr + br -> both fp16, HEAD-MAJOR [h][node][16]
__global__ __launch_bounds__(256) void gemm1_kernel(
        const float* __restrict__ x,
        const float* __restrict__ Wl, const float* __restrict__ bl,
        const float* __restrict__ Wr, const float* __restrict__ br,
        __half* __restrict__ xlh, __half* __restrict__ xrh) {
    __shared__ float xs_t[F_IN][36];      // [k][node], padded
    int t = threadIdx.x & 31;             // col-quad: combined cols 4t..4t+3
    int g = threadIdx.x >> 5;             // node-quad
    const float* Wsel = (t < 16) ? Wl : Wr;
    const float* bsel = (t < 16) ? bl : br;
    int jc = (t < 16) ? 4 * t : 4 * t - HC;
    float4 bias = *(const float4*)(bsel + jc);
    __half* table = (t < 16) ? xlh : xrh;
    size_t hbase = (size_t)(jc >> 4) * N_NODES;   // head-major base
    int hoff = jc & 15;                           // 0,4,8,12

    int n0 = blockIdx.x * 32;             // N_NODES = 32*3125 exactly
    int row = threadIdx.x >> 3;
    int cq  = threadIdx.x & 7;
#pragma unroll
    for (int r = 0; r < 4; r++) {
        int c = cq * 4 + r * 32;
        float4 v = *(const float4*)(x + (size_t)(n0 + row) * F_IN + c);
        xs_t[c + 0][row] = v.x;
        xs_t[c + 1][row] = v.y;
        xs_t[c + 2][row] = v.z;
        xs_t[c + 3][row] = v.w;
    }
    __syncthreads();
    int nb = g * 4;
    float4 a0 = bias, a1 = bias, a2 = bias, a3 = bias;
#pragma unroll 4
    for (int k = 0; k < F_IN; k++) {
        float4 w  = *(const float4*)(Wsel + k * HC + jc);
        float4 xv = *(const float4*)&xs_t[k][nb];
        a0.x += w.x * xv.x; a0.y += w.y * xv.x; a0.z += w.z * xv.x; a0.w += w.w * xv.x;
        a1.x += w.x * xv.y; a1.y += w.y * xv.y; a1.z += w.z * xv.y; a1.w += w.w * xv.y;
        a2.x += w.x * xv.z; a2.y += w.y * xv.z; a2.z += w.z * xv.z; a2.w += w.w * xv.z;
        a3.x += w.x * xv.w; a3.y += w.y * xv.w; a3.z += w.z * xv.w; a3.w += w.w * xv.w;
    }
    float4 arr[4] = {a0, a1, a2, a3};
#pragma unroll
    for (int r = 0; r < 4; r++) {
        H2I u0, u1;
        u0.h = __floats2half2_rn(arr[r].x, arr[r].y);
        u1.h = __floats2half2_rn(arr[r].z, arr[r].w);
        *(int2*)(table + (hbase + (n0 + nb + r)) * 16 + hoff) = make_int2(u0.i, u1.i);
    }
}

// fused layer-1, HEAD-SPLIT: grid (N/4, NHEAD). One wave per (node, head).
// 16 edges/iter (4 lanes/edge, 4 ch/lane). Per-head gather table = 3.2 MB (L2-resident).
// Streaming operands use nontemporal loads. No-max softmax (bounded logits).
__global__ __launch_bounds__(256) void gat1h_kernel(
        const unsigned* __restrict__ row_start, const unsigned* __restrict__ deg,
        const int* __restrict__ ssrc, const __half* __restrict__ seah,
        const float* __restrict__ We1, const float* __restrict__ att1,
        const __half* __restrict__ xlh, const __half* __restrict__ xrh,
        __half* __restrict__ out1) {
    int wave = threadIdx.x >> 6;
    int node = blockIdx.x * 4 + wave;     // grid.x*4 == N_NODES exactly
    int h    = blockIdx.y;
    int lane = threadIdx.x & 63;
    int e = lane >> 2;                    // edge slot 0..15
    int c = lane & 3;                     // channel quad within head

    float4 we[8];
#pragma unroll
    for (int k = 0; k < 8; k++) we[k] = *(const float4*)(We1 + k * HC + h * 16 + 4 * c);
    float4 attv = *(const float4*)(att1 + h * 16 + 4 * c);
    unsigned start = row_start[node];
    unsigned cnt   = deg[node] + 1u;
    unsigned cm1   = cnt - 1u;
    v2i xrp = __builtin_nontemporal_load((const v2i*)(xrh + ((size_t)h * N_NODES + node) * 16 + 4 * c));
    float4 xrv = h4_to_f4(xrp);

    float den = 0.f;
    float4 acc = make_float4(0.f, 0.f, 0.f, 0.f);

    for (unsigned j = 0; j < cnt; j += 16) {
        unsigned o = j + (unsigned)e;
        bool valid = o < cnt;
        unsigned idx = start + (valid ? o : cm1);
        int s  = __builtin_nontemporal_load(ssrc + idx);
        v4i sp = __builtin_nontemporal_load((const v4i*)(seah + (size_t)idx * 8));
        v2i xp = *(const v2i*)(xlh + ((size_t)h * N_NODES + s) * 16 + 4 * c);  // cached gather
        float4 e0 = h8_lo(sp), e1 = h8_hi(sp);
        float4 xv = h4_to_f4(xp);
        float4 v;
        v.x = xv.x + xrv.x + e0.x*we[0].x + e0.y*we[1].x + e0.z*we[2].x + e0.w*we[3].x
                           + e1.x*we[4].x + e1.y*we[5].x + e1.z*we[6].x + e1.w*we[7].x;
        v.y = xv.y + xrv.y + e0.x*we[0].y + e0.y*we[1].y + e0.z*we[2].y + e0.w*we[3].y
                           + e1.x*we[4].y + e1.y*we[5].y + e1.z*we[6].y + e1.w*we[7].y;
        v.z = xv.z + xrv.z + e0.x*we[0].z + e0.y*we[1].z + e0.z*we[2].z + e0.w*we[3].z
                           + e1.x*we[4].z + e1.y*we[5].z + e1.z*we[6].z + e1.w*we[7].z;
        v.w = xv.w + xrv.w + e0.x*we[0].w + e0.y*we[1].w + e0.z*we[2].w + e0.w*we[3].w
                           + e1.x*we[4].w + e1.y*we[5].w + e1.z*we[6].w + e1.w*we[7].w;
        v.x = fmaxf(v.x, NEG * v.x);
        v.y = fmaxf(v.y, NEG * v.y);
        v.z = fmaxf(v.z, NEG * v.z);
        v.w = fmaxf(v.w, NEG * v.w);
        float prod = v.x*attv.x + v.y*attv.y + v.z*attv.z + v.w*attv.w;
        prod += __shfl_xor(prod, 1);
        prod += __shfl_xor(prod, 2);      // head-h logit of this edge
        float p = valid ? __expf(prod) : 0.f;   // no-max: |logit| bounded ~12
        den   += p;
        acc.x += p * xv.x;
        acc.y += p * xv.y;
        acc.z += p * xv.z;
        acc.w += p * xv.w;
    }
    // merge the 16 edge sub-streams (lane bits 2..5)
#pragma unroll
    for (int off = 4; off <= 32; off <<= 1) {
        den   += __shfl_xor(den, off);
        acc.x += __shfl_xor(acc.x, off);
        acc.y += __shfl_xor(acc.y, off);
        acc.z += __shfl_xor(acc.z, off);
        acc.w += __shfl_xor(acc.w, off);
    }
    if (e == 0) {
        float inv = 1.f / den;
        H2I u0, u1;
        u0.h = __floats2half2_rn(acc.x * inv, acc.y * inv);
        u1.h = __floats2half2_rn(acc.z * inv, acc.w * inv);
        *(int2*)(out1 + ((size_t)h * N_NODES + node) * 16 + 4 * c) = make_int2(u0.i, u1.i);
    }
}

// epilogue: o = out1 + b1; ELU; xl2/xr2 = o@Wl2/Wr2 + bias. One 16-lane group per node.
__global__ __launch_bounds__(256) void gat1e_kernel(
        const __half* __restrict__ out1, const float* __restrict__ b1,
        const float* __restrict__ Wl2, const float* __restrict__ bl2,
        const float* __restrict__ Wr2, const float* __restrict__ br2,
        float* __restrict__ xl2, float* __restrict__ xr2) {
    int wave = threadIdx.x >> 6;
    int lane = threadIdx.x & 63;
    int g  = lane >> 4;                      // node sub-slot
    int cl = lane & 15;                      // channels 4cl..4cl+3 (global)
    int node = (blockIdx.x * 4 + wave) * 4 + g;   // grid 6250 * 16 = 100000 exact
    int h = cl >> 2, q = cl & 3;
    v2i op = *(const v2i*)(out1 + ((size_t)h * N_NODES + node) * 16 + 4 * q);
    float4 o = h4_to_f4(op);
    float4 bv = *(const float4*)(b1 + 4 * cl);
    o.x += bv.x; o.y += bv.y; o.z += bv.z; o.w += bv.w;
    o.x = o.x > 0.f ? o.x : __expf(o.x) - 1.f;
    o.y = o.y > 0.f ? o.y : __expf(o.y) - 1.f;
    o.z = o.z > 0.f ? o.z : __expf(o.z) - 1.f;
    o.w = o.w > 0.f ? o.w : __expf(o.w) - 1.f;
    float4 wl = *(const float4*)(Wl2 + 4 * cl);
    float4 wr = *(const float4*)(Wr2 + 4 * cl);
    float sl = o.x*wl.x + o.y*wl.y + o.z*wl.z + o.w*wl.w;
    float sr = o.x*wr.x + o.y*wr.y + o.z*wr.z + o.w*wr.w;
#pragma unroll
    for (int off = 1; off <= 8; off <<= 1) {
        sl += __shfl_xor(sl, off);
        sr += __shfl_xor(sr, off);
    }
    if (cl == 0) {
        xl2[node] = sl + bl2[0];
        xr2[node] = sr + br2[0];
    }
}

// fused layer-2: one wave per node, lanes parallel over in-edges, no-max softmax.
__global__ __launch_bounds__(256) void gat2_kernel(
        const unsigned* __restrict__ row_start, const unsigned* __restrict__ deg,
        const int* __restrict__ sorted_src, const float* __restrict__ see2,
        const float* __restrict__ att2,
        const float* __restrict__ xl2, const float* __restrict__ xr2,
        const float* __restrict__ b2, float* __restrict__ out) {
    int node = blockIdx.x * (blockDim.x >> 6) + (threadIdx.x >> 6);
    int lane = threadIdx.x & 63;
    if (node >= N_NODES) return;
    unsigned start = row_start[node];
    unsigned cnt   = deg[node] + 1u;
    float xrv = xr2[node];
    float a2  = att2[0];
    float den = 0.f, num = 0.f;
    for (unsigned base = 0; base < cnt; base += 64) {
        unsigned idx = base + lane;
        float p = 0.f, xv = 0.f;
        if (idx < cnt) {
            int s = sorted_src[start + idx];
            float ee = see2[start + idx];
            xv = xl2[s];
            float v = xv + xrv + ee;
            v = fmaxf(v, NEG * v);
            p = __expf(a2 * v);
        }
        float pn = p * xv;
#pragma unroll
        for (int off = 1; off < 64; off <<= 1) {
            p  += __shfl_xor(p, off);
            pn += __shfl_xor(pn, off);
        }
        den += p;
        num += pn;
    }
    if (lane == 0) out[node] = num / den + b2[0];
}

extern "C" void kernel_launch(void* const* d_in, const int* in_sizes, int n_in,
                              void* d_out, int out_size, void* d_ws, size_t ws_size,
                              hipStream_t stream) {
    const float* x    = (const float*)d_in[0];
    const int*   ei   = (const int*)d_in[1];
    const float* ea   = (const float*)d_in[2];
    const float* Wl1  = (const float*)d_in[3];
    const float* bl1  = (const float*)d_in[4];
    const float* Wr1  = (const float*)d_in[5];
    const float* br1  = (const float*)d_in[6];
    const float* We1  = (const float*)d_in[7];
    const float* att1 = (const float*)d_in[8];
    const float* b1   = (const float*)d_in[9];
    const float* Wl2  = (const float*)d_in[10];
    const float* bl2  = (const float*)d_in[11];
    const float* Wr2  = (const float*)d_in[12];
    const float* br2  = (const float*)d_in[13];
    const float* We2  = (const float*)d_in[14];
    const float* att2 = (const float*)d_in[15];
    const float* b2   = (const float*)d_in[16];

    const int* src = ei;              // edge_index row 0
    const int* dst = ei + N_EDGES;    // edge_index row 1

    float* W = (float*)d_ws;
    size_t o = 0;
    float*    sum8      = W + o;               o += 8;
    float*    partials  = W + o;               o += MS_BLOCKS * 8;
    unsigned* deg       = (unsigned*)(W + o);  o += N_NODES;
    unsigned* local_inc = (unsigned*)(W + o);  o += N_NODES;
    unsigned* bsum      = (unsigned*)(W + o);  o += 128;
    unsigned* row_start = (unsigned*)(W + o);  o += N_NODES;
    unsigned* next      = (unsigned*)(W + o);  o += N_NODES;
    int*      ssrc      = (int*)(W + o);       o += N_ITEMS;
    float*    see2      = W + o;               o += N_ITEMS;
    o = (o + 3) & ~(size_t)3;                  // 16B align
    __half*   seah      = (__half*)(W + o);    o += (size_t)N_ITEMS * 4;       // 8 halves/item
    __half*   xlh       = (__half*)(W + o);    o += (size_t)N_NODES * (HC/2);  // [h][node][16] fp16
    __half*   xrh       = (__half*)(W + o);    o += (size_t)N_NODES * (HC/2);  // [h][node][16] fp16
    __half*   out1      = (__half*)(W + o);    o += (size_t)N_NODES * (HC/2);  // [h][node][16] fp16
    float*    xl2       = W + o;               o += N_NODES;
    float*    xr2       = W + o;               o += N_NODES;

    hipMemsetAsync(deg, 0, (size_t)N_NODES * sizeof(unsigned), stream);
    mean_sum_kernel<<<MS_BLOCKS, 256, 0, stream>>>(ea, dst, partials, deg);
    reduce_sum8<<<1, 64, 0, stream>>>(partials, sum8);
    scan1<<<SCAN_NB, SCAN_BS, 0, stream>>>(deg, local_inc, bsum);
    scan2<<<1, 128, 0, stream>>>(bsum);
    scan3<<<(N_NODES + 255) / 256, 256, 0, stream>>>(local_inc, deg, bsum, row_start, next);
    scatter_kernel<<<(N_ITEMS + 255) / 256, 256, 0, stream>>>(
        src, dst, ea, sum8, We2, next, ssrc, seah, see2);
    gemm1_kernel<<<N_NODES / 32, 256, 0, stream>>>(x, Wl1, bl1, Wr1, br1, xlh, xrh);
    dim3 g1(N_NODES / 4, NHEAD);
    gat1h_kernel<<<g1, 256, 0, stream>>>(
        row_start, deg, ssrc, seah, We1, att1, xlh, xrh, out1);
    gat1e_kernel<<<N_NODES / 16, 256, 0, stream>>>(
        out1, b1, Wl2, bl2, Wr2, br2, xl2, xr2);
    gat2_kernel<<<(N_NODES + 3) / 4, 256, 0, stream>>>(
        row_start, deg, ssrc, see2, att2, xl2, xr2, b2, (float*)d_out);
}

// Round 12
// 445.202 us; speedup vs baseline: 1.3064x; 1.3064x over previous
//
#include <hip/hip_runtime.h>
#include <hip/hip_fp16.h>
#include <math.h>

#define N_NODES 100000
#define N_EDGES 1600000
#define N_ITEMS (N_EDGES + N_NODES)   // edges + self loops
#define F_IN 128
#define HC 64      // H*C (layer-1 output width)
#define NEG 0.2f
#define SCAN_BS 1024
#define SCAN_NB ((N_NODES + SCAN_BS - 1) / SCAN_BS)   // 98
#define MS_BLOCKS 1024

union H2I { __half2 h; int i; };
typedef int v2i __attribute__((ext_vector_type(2)));
typedef int v4i __attribute__((ext_vector_type(4)));

__device__ __forceinline__ float4 h4_to_f4(v2i w) {
    H2I u0, u1; u0.i = w.x; u1.i = w.y;
    float2 a = __half22float2(u0.h), b = __half22float2(u1.h);
    return make_float4(a.x, a.y, b.x, b.y);
}
__device__ __forceinline__ float4 h8_lo(v4i r) {
    H2I h0, h1; h0.i = r.x; h1.i = r.y;
    float2 f0 = __half22float2(h0.h), f1 = __half22float2(h1.h);
    return make_float4(f0.x, f0.y, f1.x, f1.y);
}
__device__ __forceinline__ float4 h8_hi(v4i r) {
    H2I h2, h3; h2.i = r.z; h3.i = r.w;
    float2 f2 = __half22float2(h2.h), f3 = __half22float2(h3.h);
    return make_float4(f2.x, f2.y, f3.x, f3.y);
}

// partial sums of edge_attr columns + degree histogram (deg pre-zeroed via memsetAsync)
__global__ void mean_sum_kernel(const float* __restrict__ ea, const int* __restrict__ dst,
                                float* __restrict__ partials, unsigned* __restrict__ deg) {
    __shared__ float sh[4][8];
    int stride = gridDim.x * blockDim.x;
    float acc[8] = {0.f,0.f,0.f,0.f,0.f,0.f,0.f,0.f};
    for (int r = blockIdx.x * blockDim.x + threadIdx.x; r < N_EDGES; r += stride) {
        const float4* p = (const float4*)(ea + (size_t)r * 8);
        float4 a = p[0], b = p[1];
        acc[0] += a.x; acc[1] += a.y; acc[2] += a.z; acc[3] += a.w;
        acc[4] += b.x; acc[5] += b.y; acc[6] += b.z; acc[7] += b.w;
        atomicAdd(&deg[dst[r]], 1u);
    }
    int wid  = threadIdx.x >> 6;
    int lane = threadIdx.x & 63;
#pragma unroll
    for (int k = 0; k < 8; k++) {
        float v = acc[k];
        for (int off = 32; off; off >>= 1) v += __shfl_down(v, off);
        if (lane == 0) sh[wid][k] = v;
    }
    __syncthreads();
    if (threadIdx.x < 8) {
        float s = sh[0][threadIdx.x] + sh[1][threadIdx.x] + sh[2][threadIdx.x] + sh[3][threadIdx.x];
        partials[blockIdx.x * 8 + threadIdx.x] = s;
    }
}

// inclusive block scan of (deg+1); block 0 additionally reduces partials -> sum8
__global__ void scan1(const unsigned* __restrict__ deg, unsigned* __restrict__ local_inc,
                      unsigned* __restrict__ bsum,
                      const float* __restrict__ partials, float* __restrict__ sum8) {
    if (blockIdx.x == 0 && threadIdx.x < 64) {
        int lane = threadIdx.x;
        int c = lane & 7, g = lane >> 3;
        float s = 0.f;
        for (int b = g; b < MS_BLOCKS; b += 8) s += partials[b * 8 + c];
        s += __shfl_xor(s, 8);
        s += __shfl_xor(s, 16);
        s += __shfl_xor(s, 32);
        if (lane < 8) sum8[lane] = s;
    }
    __shared__ unsigned wsum[16];
    int i = blockIdx.x * SCAN_BS + threadIdx.x;
    int lane = threadIdx.x & 63;
    int wid  = threadIdx.x >> 6;          // 0..15
    unsigned v = (i < N_NODES) ? (deg[i] + 1u) : 0u;   // +1 = self loop
    unsigned sc = v;
#pragma unroll
    for (int off = 1; off < 64; off <<= 1) {
        unsigned t = __shfl_up(sc, off);
        if (lane >= off) sc += t;
    }
    if (lane == 63) wsum[wid] = sc;
    __syncthreads();
    if (threadIdx.x < 16) {
        unsigned w = wsum[threadIdx.x];
#pragma unroll
        for (int off = 1; off < 16; off <<= 1) {
            unsigned t = __shfl_up(w, off);
            if ((int)threadIdx.x >= off) w += t;
        }
        wsum[threadIdx.x] = w;
    }
    __syncthreads();
    unsigned base = wid ? wsum[wid - 1] : 0u;
    sc += base;
    if (i < N_NODES) local_inc[i] = sc;
    if (threadIdx.x == SCAN_BS - 1) bsum[blockIdx.x] = sc;
}

// fused scan2+scan3: every block re-scans the 98 block sums, then finalizes rows
__global__ void scan23(const unsigned* __restrict__ local_inc, const unsigned* __restrict__ deg,
                       const unsigned* __restrict__ bsum,
                       unsigned* __restrict__ row_start, unsigned* __restrict__ next) {
    __shared__ unsigned tmp[128];
    int t = threadIdx.x;
    if (t < 128) tmp[t] = (t < SCAN_NB) ? bsum[t] : 0u;
    __syncthreads();
    for (int off = 1; off < 128; off <<= 1) {
        unsigned add = 0u;
        if (t < 128 && t >= off) add = tmp[t - off];
        __syncthreads();
        if (t < 128) tmp[t] += add;
        __syncthreads();
    }
    int i = blockIdx.x * blockDim.x + t;
    if (i >= N_NODES) return;
    int b = i >> 10;                      // i / SCAN_BS
    unsigned base = b ? tmp[b - 1] : 0u;  // exclusive
    unsigned v = local_inc[i] - (deg[i] + 1u) + base;
    row_start[i] = v;
    next[i] = v;
}

// scatter edges (+ self loops) into destination-sorted order:
// rec = {src, see2-bits} (one 8B store), seah = fp16 edge attrs (one int4 store)
__global__ void scatter_kernel(const int* __restrict__ src, const int* __restrict__ dst,
                               const float* __restrict__ ea, const float* __restrict__ sum8,
                               const float* __restrict__ We2,
                               unsigned* __restrict__ next,
                               int* __restrict__ rec, __half* __restrict__ seah) {
    int item = blockIdx.x * blockDim.x + threadIdx.x;
    if (item >= N_ITEMS) return;
    int s, d;
    float4 a, b;
    if (item < N_EDGES) {
        s = src[item]; d = dst[item];
        const float4* p = (const float4*)(ea + (size_t)item * 8);
        a = p[0]; b = p[1];
    } else {
        s = d = item - N_EDGES;
        const float inv = 1.0f / N_EDGES;
        a = make_float4(sum8[0]*inv, sum8[1]*inv, sum8[2]*inv, sum8[3]*inv);
        b = make_float4(sum8[4]*inv, sum8[5]*inv, sum8[6]*inv, sum8[7]*inv);
    }
    float ee2 = a.x*We2[0] + a.y*We2[1] + a.z*We2[2] + a.w*We2[3]
              + b.x*We2[4] + b.y*We2[5] + b.z*We2[6] + b.w*We2[7];
    unsigned pos = atomicAdd(&next[d], 1u);
    v2i rr; rr.x = s; rr.y = __float_as_int(ee2);
    *(v2i*)(rec + (size_t)pos * 2) = rr;
    H2I p0, p1, p2, p3;
    p0.h = __floats2half2_rn(a.x, a.y);
    p1.h = __floats2half2_rn(a.z, a.w);
    p2.h = __floats2half2_rn(b.x, b.y);
    p3.h = __floats2half2_rn(b.z, b.w);
    *(int4*)(seah + (size_t)pos * 8) = make_int4(p0.i, p1.i, p2.i, p3.i);
}

// xl = x@Wl + bl (stored fp16); xr = x@Wr + br (f32)
__global__ __launch_bounds__(256) void gemm1_kernel(
        const float* __restrict__ x,
        const float* __restrict__ Wl, const float* __restrict__ bl,
        const float* __restrict__ Wr, const float* __restrict__ br,
        __half* __restrict__ xlh, float* __restrict__ xr) {
    __shared__ float xs_t[F_IN][36];      // [k][node], padded
    int t = threadIdx.x & 31;
    int g = threadIdx.x >> 5;
    const float* Wsel = (t < 16) ? Wl : Wr;
    const float* bsel = (t < 16) ? bl : br;
    int jc = (t < 16) ? 4 * t : 4 * t - HC;
    float4 bias = *(const float4*)(bsel + jc);

    int n0 = blockIdx.x * 32;             // N_NODES = 32*3125 exactly
    int row = threadIdx.x >> 3;
    int cq  = threadIdx.x & 7;
#pragma unroll
    for (int r = 0; r < 4; r++) {
        int c = cq * 4 + r * 32;
        float4 v = *(const float4*)(x + (size_t)(n0 + row) * F_IN + c);
        xs_t[c + 0][row] = v.x;
        xs_t[c + 1][row] = v.y;
        xs_t[c + 2][row] = v.z;
        xs_t[c + 3][row] = v.w;
    }
    __syncthreads();
    int nb = g * 4;
    float4 a0 = bias, a1 = bias, a2 = bias, a3 = bias;
#pragma unroll 4
    for (int k = 0; k < F_IN; k++) {
        float4 w  = *(const float4*)(Wsel + k * HC + jc);
        float4 xv = *(const float4*)&xs_t[k][nb];
        a0.x += w.x * xv.x; a0.y += w.y * xv.x; a0.z += w.z * xv.x; a0.w += w.w * xv.x;
        a1.x += w.x * xv.y; a1.y += w.y * xv.y; a1.z += w.z * xv.y; a1.w += w.w * xv.y;
        a2.x += w.x * xv.z; a2.y += w.y * xv.z; a2.z += w.z * xv.z; a2.w += w.w * xv.z;
        a3.x += w.x * xv.w; a3.y += w.y * xv.w; a3.z += w.z * xv.w; a3.w += w.w * xv.w;
    }
    if (t < 16) {
        float4 arr[4] = {a0, a1, a2, a3};
#pragma unroll
        for (int r = 0; r < 4; r++) {
            H2I u0, u1;
            u0.h = __floats2half2_rn(arr[r].x, arr[r].y);
            u1.h = __floats2half2_rn(arr[r].z, arr[r].w);
            *(int2*)(xlh + (size_t)(n0 + nb + r) * HC + jc) = make_int2(u0.i, u1.i);
        }
    } else {
        *(float4*)(xr + (size_t)(n0 + nb + 0) * HC + jc) = a0;
        *(float4*)(xr + (size_t)(n0 + nb + 1) * HC + jc) = a1;
        *(float4*)(xr + (size_t)(n0 + nb + 2) * HC + jc) = a2;
        *(float4*)(xr + (size_t)(n0 + nb + 3) * HC + jc) = a3;
    }
}

// no-max edge update: linear accumulation (self loop guarantees den > 0)
__device__ __forceinline__ void edge_update_nm(const float4* __restrict__ we,
                                               const float4& attv, const float4& xrv,
                                               bool valid, const float4& ea0, const float4& ea1,
                                               const float4& xlv,
                                               float& den, float4& acc) {
    float4 v;
    v.x = xlv.x + xrv.x + ea0.x*we[0].x + ea0.y*we[1].x + ea0.z*we[2].x + ea0.w*we[3].x
                        + ea1.x*we[4].x + ea1.y*we[5].x + ea1.z*we[6].x + ea1.w*we[7].x;
    v.y = xlv.y + xrv.y + ea0.x*we[0].y + ea0.y*we[1].y + ea0.z*we[2].y + ea0.w*we[3].y
                        + ea1.x*we[4].y + ea1.y*we[5].y + ea1.z*we[6].y + ea1.w*we[7].y;
    v.z = xlv.z + xrv.z + ea0.x*we[0].z + ea0.y*we[1].z + ea0.z*we[2].z + ea0.w*we[3].z
                        + ea1.x*we[4].z + ea1.y*we[5].z + ea1.z*we[6].z + ea1.w*we[7].z;
    v.w = xlv.w + xrv.w + ea0.x*we[0].w + ea0.y*we[1].w + ea0.z*we[2].w + ea0.w*we[3].w
                        + ea1.x*we[4].w + ea1.y*we[5].w + ea1.z*we[6].w + ea1.w*we[7].w;
    v.x = fmaxf(v.x, NEG * v.x);
    v.y = fmaxf(v.y, NEG * v.y);
    v.z = fmaxf(v.z, NEG * v.z);
    v.w = fmaxf(v.w, NEG * v.w);
    float prod = v.x*attv.x + v.y*attv.y + v.z*attv.z + v.w*attv.w;
    prod += __shfl_xor(prod, 1);
    prod += __shfl_xor(prod, 2);      // per-head logit in each 4-lane cluster
    float p = valid ? __expf(prod) : 0.f;
    den   += p;
    acc.x += p * xlv.x;
    acc.y += p * xlv.y;
    acc.z += p * xlv.z;
    acc.w += p * xlv.w;
}

// fused layer-1: one wave per node, 8 edges/iter as two streams, depth-1 prefetch.
// fp16 gathers, f32 math, no-max softmax. Epilogue: bias+ELU+layer-2 projections.
__global__ void gat1_kernel(const unsigned* __restrict__ row_start, const unsigned* __restrict__ deg,
                            const int* __restrict__ rec, const __half* __restrict__ seah,
                            const float* __restrict__ We1, const float* __restrict__ att1,
                            const float* __restrict__ b1,
                            const __half* __restrict__ xlh, const float* __restrict__ xr,
                            const float* __restrict__ Wl2, const float* __restrict__ bl2,
                            const float* __restrict__ Wr2, const float* __restrict__ br2,
                            float* __restrict__ xl2, float* __restrict__ xr2) {
    int node = blockIdx.x * (blockDim.x >> 6) + (threadIdx.x >> 6);
    int lane = threadIdx.x & 63;
    if (node >= N_NODES) return;
    int g  = lane >> 4;          // edge sub-stream 0..3
    int cl = lane & 15;          // channel-slot: channels 4cl..4cl+3
    unsigned start = row_start[node];
    unsigned cnt   = deg[node] + 1u;
    unsigned cm1   = cnt - 1u;

    float4 we[8];
#pragma unroll
    for (int k = 0; k < 8; k++) we[k] = *(const float4*)(We1 + k * HC + 4 * cl);
    float4 attv = *(const float4*)(att1 + 4 * cl);
    float4 xrv  = *(const float4*)(xr + (size_t)node * HC + 4 * cl);

    float denA = 0.f, denB = 0.f;
    float4 accA = make_float4(0.f,0.f,0.f,0.f), accB = make_float4(0.f,0.f,0.f,0.f);

#define IDXA(J) (start + min((J) + (unsigned)g, cm1))
#define IDXB(J) (start + min((J) + 4u + (unsigned)g, cm1))
    // prologue: depth-1 prefetch, two streams
    unsigned iA = IDXA(0u), iB = IDXB(0u);
    v2i rA = __builtin_nontemporal_load((const v2i*)(rec + (size_t)iA * 2));
    v2i rB = __builtin_nontemporal_load((const v2i*)(rec + (size_t)iB * 2));
    v4i spA = __builtin_nontemporal_load((const v4i*)(seah + (size_t)iA * 8));
    v4i spB = __builtin_nontemporal_load((const v4i*)(seah + (size_t)iB * 8));
    v2i xpA = *(const v2i*)(xlh + (size_t)rA.x * HC + 4 * cl);
    v2i xpB = *(const v2i*)(xlh + (size_t)rB.x * HC + 4 * cl);

    for (unsigned j = 0; j < cnt; j += 8) {
        float4 e0A = h8_lo(spA), e1A = h8_hi(spA), xA = h4_to_f4(xpA);
        float4 e0B = h8_lo(spB), e1B = h8_hi(spB), xB = h4_to_f4(xpB);
        bool vA = (j + g) < cnt, vB = (j + 4 + g) < cnt;
        if (j + 8 < cnt) {
            iA = IDXA(j + 8); iB = IDXB(j + 8);
            rA = __builtin_nontemporal_load((const v2i*)(rec + (size_t)iA * 2));
            rB = __builtin_nontemporal_load((const v2i*)(rec + (size_t)iB * 2));
            spA = __builtin_nontemporal_load((const v4i*)(seah + (size_t)iA * 8));
            spB = __builtin_nontemporal_load((const v4i*)(seah + (size_t)iB * 8));
            xpA = *(const v2i*)(xlh + (size_t)rA.x * HC + 4 * cl);
            xpB = *(const v2i*)(xlh + (size_t)rB.x * HC + 4 * cl);
        }
        edge_update_nm(we, attv, xrv, vA, e0A, e1A, xA, denA, accA);
        edge_update_nm(we, attv, xrv, vB, e0B, e1B, xB, denB, accB);
    }
#undef IDXA
#undef IDXB

    float den = denA + denB;
    float4 acc;
    acc.x = accA.x + accB.x;
    acc.y = accA.y + accB.y;
    acc.z = accA.z + accB.z;
    acc.w = accA.w + accB.w;

    // merge the 4 g-streams (lanes differing in bits 4,5) — plain sums
    den   += __shfl_xor(den, 16);   den   += __shfl_xor(den, 32);
    acc.x += __shfl_xor(acc.x, 16); acc.x += __shfl_xor(acc.x, 32);
    acc.y += __shfl_xor(acc.y, 16); acc.y += __shfl_xor(acc.y, 32);
    acc.z += __shfl_xor(acc.z, 16); acc.z += __shfl_xor(acc.z, 32);
    acc.w += __shfl_xor(acc.w, 16); acc.w += __shfl_xor(acc.w, 32);

    float4 b1v  = *(const float4*)(b1 + 4 * cl);
    float4 wl2v = *(const float4*)(Wl2 + 4 * cl);
    float4 wr2v = *(const float4*)(Wr2 + 4 * cl);
    float inv_den = 1.f / den;
    float4 o;
    o.x = acc.x * inv_den + b1v.x;
    o.y = acc.y * inv_den + b1v.y;
    o.z = acc.z * inv_den + b1v.z;
    o.w = acc.w * inv_den + b1v.w;
    o.x = o.x > 0.f ? o.x : __expf(o.x) - 1.f;   // ELU
    o.y = o.y > 0.f ? o.y : __expf(o.y) - 1.f;
    o.z = o.z > 0.f ? o.z : __expf(o.z) - 1.f;
    o.w = o.w > 0.f ? o.w : __expf(o.w) - 1.f;
    float sl = o.x*wl2v.x + o.y*wl2v.y + o.z*wl2v.z + o.w*wl2v.w;
    float sr = o.x*wr2v.x + o.y*wr2v.y + o.z*wr2v.z + o.w*wr2v.w;
#pragma unroll
    for (int off = 1; off <= 8; off <<= 1) {
        sl += __shfl_xor(sl, off);
        sr += __shfl_xor(sr, off);
    }
    if (lane == 0) {
        xl2[node] = sl + bl2[0];
        xr2[node] = sr + br2[0];
    }
}

// fused layer-2: 16 lanes per node (4 nodes/wave), no-max softmax.
__global__ __launch_bounds__(256) void gat2_kernel(
        const unsigned* __restrict__ row_start, const unsigned* __restrict__ deg,
        const int* __restrict__ rec, const float* __restrict__ att2,
        const float* __restrict__ xl2, const float* __restrict__ xr2,
        const float* __restrict__ b2, float* __restrict__ out) {
    int wave = threadIdx.x >> 6;
    int lane = threadIdx.x & 63;
    int sub  = lane >> 4;                 // node within wave
    int l    = lane & 15;
    int node = (blockIdx.x * 4 + wave) * 4 + sub;   // grid 6250 * 16 = 100000 exact
    unsigned start = row_start[node];
    unsigned cnt   = deg[node] + 1u;
    float xrv = xr2[node];
    float a2  = att2[0];
    float den = 0.f, num = 0.f;
    for (unsigned idx = (unsigned)l; idx < cnt; idx += 16) {
        v2i r = __builtin_nontemporal_load((const v2i*)(rec + (size_t)(start + idx) * 2));
        float ee = __int_as_float(r.y);
        float xv = xl2[r.x];
        float v = xv + xrv + ee;
        v = fmaxf(v, NEG * v);
        float p = __expf(a2 * v);
        den += p;
        num += p * xv;
    }
#pragma unroll
    for (int off = 1; off <= 8; off <<= 1) {
        den += __shfl_xor(den, off);
        num += __shfl_xor(num, off);
    }
    if (l == 0) out[node] = num / den + b2[0];
}

extern "C" void kernel_launch(void* const* d_in, const int* in_sizes, int n_in,
                              void* d_out, int out_size, void* d_ws, size_t ws_size,
                              hipStream_t stream) {
    const float* x    = (const float*)d_in[0];
    const int*   ei   = (const int*)d_in[1];
    const float* ea   = (const float*)d_in[2];
    const float* Wl1  = (const float*)d_in[3];
    const float* bl1  = (const float*)d_in[4];
    const float* Wr1  = (const float*)d_in[5];
    const float* br1  = (const float*)d_in[6];
    const float* We1  = (const float*)d_in[7];
    const float* att1 = (const float*)d_in[8];
    const float* b1   = (const float*)d_in[9];
    const float* Wl2  = (const float*)d_in[10];
    const float* bl2  = (const float*)d_in[11];
    const float* Wr2  = (const float*)d_in[12];
    const float* br2  = (const float*)d_in[13];
    const float* We2  = (const float*)d_in[14];
    const float* att2 = (const float*)d_in[15];
    const float* b2   = (const float*)d_in[16];

    const int* src = ei;              // edge_index row 0
    const int* dst = ei + N_EDGES;    // edge_index row 1

    float* W = (float*)d_ws;
    size_t o = 0;
    float*    sum8      = W + o;               o += 8;
    float*    partials  = W + o;               o += MS_BLOCKS * 8;
    unsigned* deg       = (unsigned*)(W + o);  o += N_NODES;
    unsigned* local_inc = (unsigned*)(W + o);  o += N_NODES;
    unsigned* bsum      = (unsigned*)(W + o);  o += 128;
    unsigned* row_start = (unsigned*)(W + o);  o += N_NODES;
    unsigned* next      = (unsigned*)(W + o);  o += N_NODES;
    o = (o + 3) & ~(size_t)3;                  // 16B align
    int*      rec       = (int*)(W + o);       o += (size_t)N_ITEMS * 2;      // {src, see2}
    __half*   seah      = (__half*)(W + o);    o += (size_t)N_ITEMS * 4;      // 8 halves/item
    __half*   xlh       = (__half*)(W + o);    o += (size_t)N_NODES * (HC/2); // fp16 xl
    float*    xr1       = W + o;               o += (size_t)N_NODES * HC;
    float*    xl2       = W + o;               o += N_NODES;
    float*    xr2       = W + o;               o += N_NODES;

    hipMemsetAsync(deg, 0, (size_t)N_NODES * sizeof(unsigned), stream);
    mean_sum_kernel<<<MS_BLOCKS, 256, 0, stream>>>(ea, dst, partials, deg);
    scan1<<<SCAN_NB, SCAN_BS, 0, stream>>>(deg, local_inc, bsum, partials, sum8);
    scan23<<<(N_NODES + 255) / 256, 256, 0, stream>>>(local_inc, deg, bsum, row_start, next);
    scatter_kernel<<<(N_ITEMS + 255) / 256, 256, 0, stream>>>(
        src, dst, ea, sum8, We2, next, rec, seah);
    gemm1_kernel<<<N_NODES / 32, 256, 0, stream>>>(x, Wl1, bl1, Wr1, br1, xlh, xr1);
    gat1_kernel<<<(N_NODES + 3) / 4, 256, 0, stream>>>(
        row_start, deg, rec, seah, We1, att1, b1, xlh, xr1,
        Wl2, bl2, Wr2, br2, xl2, xr2);
    gat2_kernel<<<N_NODES / 16, 256, 0, stream>>>(
        row_start, deg, rec, att2, xl2, xr2, b2, (float*)d_out);
}

// Round 14
// 405.775 us; speedup vs baseline: 1.4334x; 1.0972x over previous
//
#include <hip/hip_runtime.h>
#include <hip/hip_fp16.h>
#include <math.h>

#define N_NODES 100000
#define N_EDGES 1600000
#define N_ITEMS (N_EDGES + N_NODES)   // edges + self loops
#define F_IN 128
#define HC 64      // H*C (layer-1 output width)
#define NEG 0.2f
#define SCAN_BS 1024
#define SCAN_NB ((N_NODES + SCAN_BS - 1) / SCAN_BS)   // 98
#define MS_BLOCKS 1024

union H2I { __half2 h; int i; };
typedef int v2i __attribute__((ext_vector_type(2)));
typedef int v4i __attribute__((ext_vector_type(4)));

// packed fp16 max (header lacks __hmax2 on this ROCm)
__device__ __forceinline__ __half2 hmax2(__half2 a, __half2 b) {
    H2I ua, ub, uc; ua.h = a; ub.h = b;
    asm("v_pk_max_f16 %0, %1, %2" : "=v"(uc.i) : "v"(ua.i), "v"(ub.i));
    return uc.h;
}

// partial sums of edge_attr columns + degree histogram (deg pre-zeroed via memsetAsync)
__global__ void mean_sum_kernel(const float* __restrict__ ea, const int* __restrict__ dst,
                                float* __restrict__ partials, unsigned* __restrict__ deg) {
    __shared__ float sh[4][8];
    int stride = gridDim.x * blockDim.x;
    float acc[8] = {0.f,0.f,0.f,0.f,0.f,0.f,0.f,0.f};
    for (int r = blockIdx.x * blockDim.x + threadIdx.x; r < N_EDGES; r += stride) {
        const float4* p = (const float4*)(ea + (size_t)r * 8);
        float4 a = p[0], b = p[1];
        acc[0] += a.x; acc[1] += a.y; acc[2] += a.z; acc[3] += a.w;
        acc[4] += b.x; acc[5] += b.y; acc[6] += b.z; acc[7] += b.w;
        atomicAdd(&deg[dst[r]], 1u);
    }
    int wid  = threadIdx.x >> 6;
    int lane = threadIdx.x & 63;
#pragma unroll
    for (int k = 0; k < 8; k++) {
        float v = acc[k];
        for (int off = 32; off; off >>= 1) v += __shfl_down(v, off);
        if (lane == 0) sh[wid][k] = v;
    }
    __syncthreads();
    if (threadIdx.x < 8) {
        float s = sh[0][threadIdx.x] + sh[1][threadIdx.x] + sh[2][threadIdx.x] + sh[3][threadIdx.x];
        partials[blockIdx.x * 8 + threadIdx.x] = s;
    }
}

// inclusive block scan of (deg+1); block 0 additionally reduces partials -> sum8
__global__ void scan1(const unsigned* __restrict__ deg, unsigned* __restrict__ local_inc,
                      unsigned* __restrict__ bsum,
                      const float* __restrict__ partials, float* __restrict__ sum8) {
    if (blockIdx.x == 0 && threadIdx.x < 64) {
        int lane = threadIdx.x;
        int c = lane & 7, g = lane >> 3;
        float s = 0.f;
        for (int b = g; b < MS_BLOCKS; b += 8) s += partials[b * 8 + c];
        s += __shfl_xor(s, 8);
        s += __shfl_xor(s, 16);
        s += __shfl_xor(s, 32);
        if (lane < 8) sum8[lane] = s;
    }
    __shared__ unsigned wsum[16];
    int i = blockIdx.x * SCAN_BS + threadIdx.x;
    int lane = threadIdx.x & 63;
    int wid  = threadIdx.x >> 6;          // 0..15
    unsigned v = (i < N_NODES) ? (deg[i] + 1u) : 0u;   // +1 = self loop
    unsigned sc = v;
#pragma unroll
    for (int off = 1; off < 64; off <<= 1) {
        unsigned t = __shfl_up(sc, off);
        if (lane >= off) sc += t;
    }
    if (lane == 63) wsum[wid] = sc;
    __syncthreads();
    if (threadIdx.x < 16) {
        unsigned w = wsum[threadIdx.x];
#pragma unroll
        for (int off = 1; off < 16; off <<= 1) {
            unsigned t = __shfl_up(w, off);
            if ((int)threadIdx.x >= off) w += t;
        }
        wsum[threadIdx.x] = w;
    }
    __syncthreads();
    unsigned base = wid ? wsum[wid - 1] : 0u;
    sc += base;
    if (i < N_NODES) local_inc[i] = sc;
    if (threadIdx.x == SCAN_BS - 1) bsum[blockIdx.x] = sc;
}

// fused scan2+scan3: every block re-scans the 98 block sums, then finalizes rows
__global__ void scan23(const unsigned* __restrict__ local_inc, const unsigned* __restrict__ deg,
                       const unsigned* __restrict__ bsum,
                       unsigned* __restrict__ row_start, unsigned* __restrict__ next) {
    __shared__ unsigned tmp[128];
    int t = threadIdx.x;
    if (t < 128) tmp[t] = (t < SCAN_NB) ? bsum[t] : 0u;
    __syncthreads();
    for (int off = 1; off < 128; off <<= 1) {
        unsigned add = 0u;
        if (t < 128 && t >= off) add = tmp[t - off];
        __syncthreads();
        if (t < 128) tmp[t] += add;
        __syncthreads();
    }
    int i = blockIdx.x * blockDim.x + t;
    if (i >= N_NODES) return;
    int b = i >> 10;                      // i / SCAN_BS
    unsigned base = b ? tmp[b - 1] : 0u;  // exclusive
    unsigned v = local_inc[i] - (deg[i] + 1u) + base;
    row_start[i] = v;
    next[i] = v;
}

// scatter edges (+ self loops) into destination-sorted 32B AoS records:
// rec32[pos] = {src, see2-bits, ea0..7 fp16} — one cache line per edge.
__global__ void scatter_kernel(const int* __restrict__ src, const int* __restrict__ dst,
                               const float* __restrict__ ea, const float* __restrict__ sum8,
                               const float* __restrict__ We2,
                               unsigned* __restrict__ next,
                               int* __restrict__ rec32) {
    int item = blockIdx.x * blockDim.x + threadIdx.x;
    if (item >= N_ITEMS) return;
    int s, d;
    float4 a, b;
    if (item < N_EDGES) {
        s = src[item]; d = dst[item];
        const float4* p = (const float4*)(ea + (size_t)item * 8);
        a = p[0]; b = p[1];
    } else {
        s = d = item - N_EDGES;
        const float inv = 1.0f / N_EDGES;
        a = make_float4(sum8[0]*inv, sum8[1]*inv, sum8[2]*inv, sum8[3]*inv);
        b = make_float4(sum8[4]*inv, sum8[5]*inv, sum8[6]*inv, sum8[7]*inv);
    }
    float ee2 = a.x*We2[0] + a.y*We2[1] + a.z*We2[2] + a.w*We2[3]
              + b.x*We2[4] + b.y*We2[5] + b.z*We2[6] + b.w*We2[7];
    unsigned pos = atomicAdd(&next[d], 1u);
    H2I e01, e23, e45, e67;
    e01.h = __floats2half2_rn(a.x, a.y);
    e23.h = __floats2half2_rn(a.z, a.w);
    e45.h = __floats2half2_rn(b.x, b.y);
    e67.h = __floats2half2_rn(b.z, b.w);
    int* base = rec32 + (size_t)pos * 8;
    v4i st1; st1.x = s; st1.y = __float_as_int(ee2); st1.z = e01.i; st1.w = e23.i;
    *(v4i*)base = st1;
    v2i st2; st2.x = e45.i; st2.y = e67.i;
    *(v2i*)(base + 4) = st2;
}

// xl = x@Wl + bl ; xr = x@Wr + br — both stored fp16 [node][64]
__global__ __launch_bounds__(256) void gemm1_kernel(
        const float* __restrict__ x,
        const float* __restrict__ Wl, const float* __restrict__ bl,
        const float* __restrict__ Wr, const float* __restrict__ br,
        __half* __restrict__ xlh, __half* __restrict__ xrh) {
    __shared__ float xs_t[F_IN][36];      // [k][node], padded
    int t = threadIdx.x & 31;
    int g = threadIdx.x >> 5;
    const float* Wsel = (t < 16) ? Wl : Wr;
    const float* bsel = (t < 16) ? bl : br;
    int jc = (t < 16) ? 4 * t : 4 * t - HC;
    float4 bias = *(const float4*)(bsel + jc);
    __half* table = (t < 16) ? xlh : xrh;

    int n0 = blockIdx.x * 32;             // N_NODES = 32*3125 exactly
    int row = threadIdx.x >> 3;
    int cq  = threadIdx.x & 7;
#pragma unroll
    for (int r = 0; r < 4; r++) {
        int c = cq * 4 + r * 32;
        float4 v = *(const float4*)(x + (size_t)(n0 + row) * F_IN + c);
        xs_t[c + 0][row] = v.x;
        xs_t[c + 1][row] = v.y;
        xs_t[c + 2][row] = v.z;
        xs_t[c + 3][row] = v.w;
    }
    __syncthreads();
    int nb = g * 4;
    float4 a0 = bias, a1 = bias, a2 = bias, a3 = bias;
#pragma unroll 4
    for (int k = 0; k < F_IN; k++) {
        float4 w  = *(const float4*)(Wsel + k * HC + jc);
        float4 xv = *(const float4*)&xs_t[k][nb];
        a0.x += w.x * xv.x; a0.y += w.y * xv.x; a0.z += w.z * xv.x; a0.w += w.w * xv.x;
        a1.x += w.x * xv.y; a1.y += w.y * xv.y; a1.z += w.z * xv.y; a1.w += w.w * xv.y;
        a2.x += w.x * xv.z; a2.y += w.y * xv.z; a2.z += w.z * xv.z; a2.w += w.w * xv.z;
        a3.x += w.x * xv.w; a3.y += w.y * xv.w; a3.z += w.z * xv.w; a3.w += w.w * xv.w;
    }
    float4 arr[4] = {a0, a1, a2, a3};
#pragma unroll
    for (int r = 0; r < 4; r++) {
        H2I u0, u1;
        u0.h = __floats2half2_rn(arr[r].x, arr[r].y);
        u1.h = __floats2half2_rn(arr[r].z, arr[r].w);
        *(int2*)(table + (size_t)(n0 + nb + r) * HC + jc) = make_int2(u0.i, u1.i);
    }
}

// packed-fp16 edge update (no-max softmax; self loop guarantees den > 0)
__device__ __forceinline__ void edge_update_h(const __half2* __restrict__ weA,
                                              const __half2* __restrict__ weB,
                                              __half2 attA, __half2 attB,
                                              __half2 xr2a, __half2 xr2b,
                                              bool valid, v4i L1, v2i L2, v2i xp,
                                              float& den, float4& acc) {
    H2I ea01, ea23, ea45, ea67, xl01, xl23;
    ea01.i = L1.z; ea23.i = L1.w; ea45.i = L2.x; ea67.i = L2.y;
    xl01.i = xp.x; xl23.i = xp.y;
    __half2 va = __hadd2(xl01.h, xr2a);
    __half2 vb = __hadd2(xl23.h, xr2b);
    __half2 e;
    e = __low2half2(ea01.h);  va = __hfma2(e, weA[0], va); vb = __hfma2(e, weB[0], vb);
    e = __high2half2(ea01.h); va = __hfma2(e, weA[1], va); vb = __hfma2(e, weB[1], vb);
    e = __low2half2(ea23.h);  va = __hfma2(e, weA[2], va); vb = __hfma2(e, weB[2], vb);
    e = __high2half2(ea23.h); va = __hfma2(e, weA[3], va); vb = __hfma2(e, weB[3], vb);
    e = __low2half2(ea45.h);  va = __hfma2(e, weA[4], va); vb = __hfma2(e, weB[4], vb);
    e = __high2half2(ea45.h); va = __hfma2(e, weA[5], va); vb = __hfma2(e, weB[5], vb);
    e = __low2half2(ea67.h);  va = __hfma2(e, weA[6], va); vb = __hfma2(e, weB[6], vb);
    e = __high2half2(ea67.h); va = __hfma2(e, weA[7], va); vb = __hfma2(e, weB[7], vb);
    const __half2 k02 = __float2half2_rn(NEG);
    va = hmax2(va, __hmul2(va, k02));        // leakyrelu
    vb = hmax2(vb, __hmul2(vb, k02));
    __half2 pd = __hfma2(vb, attB, __hmul2(va, attA));
    float2 pf = __half22float2(pd);
    float prod = pf.x + pf.y;
    prod += __shfl_xor(prod, 1);
    prod += __shfl_xor(prod, 2);             // per-head logit in each 4-lane cluster
    float p = valid ? __expf(prod) : 0.f;
    float2 xa = __half22float2(xl01.h), xb = __half22float2(xl23.h);
    den   += p;
    acc.x += p * xa.x;
    acc.y += p * xa.y;
    acc.z += p * xb.x;
    acc.w += p * xb.y;
}

// fused layer-1: one wave per node, 8 edges/iter as two streams, depth-1 prefetch.
// fp16 packed math, f32 softmax accumulation, no-max. Epilogue: bias+ELU+layer-2 proj.
__global__ void gat1_kernel(const unsigned* __restrict__ row_start, const unsigned* __restrict__ deg,
                            const int* __restrict__ rec32,
                            const float* __restrict__ We1, const float* __restrict__ att1,
                            const float* __restrict__ b1,
                            const __half* __restrict__ xlh, const __half* __restrict__ xrh,
                            const float* __restrict__ Wl2, const float* __restrict__ bl2,
                            const float* __restrict__ Wr2, const float* __restrict__ br2,
                            float* __restrict__ xl2, float* __restrict__ xr2) {
    int node = blockIdx.x * (blockDim.x >> 6) + (threadIdx.x >> 6);
    int lane = threadIdx.x & 63;
    if (node >= N_NODES) return;
    int g  = lane >> 4;          // edge sub-stream 0..3
    int cl = lane & 15;          // channel-slot: channels 4cl..4cl+3
    unsigned start = row_start[node];
    unsigned cnt   = deg[node] + 1u;
    unsigned cm1   = cnt - 1u;

    __half2 weA[8], weB[8];
#pragma unroll
    for (int k = 0; k < 8; k++) {
        float4 w = *(const float4*)(We1 + k * HC + 4 * cl);
        weA[k] = __floats2half2_rn(w.x, w.y);
        weB[k] = __floats2half2_rn(w.z, w.w);
    }
    float4 at = *(const float4*)(att1 + 4 * cl);
    __half2 attA = __floats2half2_rn(at.x, at.y);
    __half2 attB = __floats2half2_rn(at.z, at.w);
    v2i xrp = *(const v2i*)(xrh + (size_t)node * HC + 4 * cl);
    H2I xru0, xru1; xru0.i = xrp.x; xru1.i = xrp.y;
    __half2 xr2a = xru0.h, xr2b = xru1.h;

    float denA = 0.f, denB = 0.f;
    float4 accA = make_float4(0.f,0.f,0.f,0.f), accB = make_float4(0.f,0.f,0.f,0.f);

#define IDXA(J) (start + min((J) + (unsigned)g, cm1))
#define IDXB(J) (start + min((J) + 4u + (unsigned)g, cm1))
    // prologue: depth-1 prefetch, two streams
    unsigned iA = IDXA(0u), iB = IDXB(0u);
    v4i L1A = __builtin_nontemporal_load((const v4i*)(rec32 + (size_t)iA * 8));
    v4i L1B = __builtin_nontemporal_load((const v4i*)(rec32 + (size_t)iB * 8));
    v2i L2A = __builtin_nontemporal_load((const v2i*)(rec32 + (size_t)iA * 8 + 4));
    v2i L2B = __builtin_nontemporal_load((const v2i*)(rec32 + (size_t)iB * 8 + 4));
    v2i xpA = *(const v2i*)(xlh + (size_t)L1A.x * HC + 4 * cl);
    v2i xpB = *(const v2i*)(xlh + (size_t)L1B.x * HC + 4 * cl);

    for (unsigned j = 0; j < cnt; j += 8) {
        v4i c1A = L1A, c1B = L1B;
        v2i c2A = L2A, c2B = L2B, cxA = xpA, cxB = xpB;
        bool vA = (j + g) < cnt, vB = (j + 4 + g) < cnt;
        if (j + 8 < cnt) {
            iA = IDXA(j + 8); iB = IDXB(j + 8);
            L1A = __builtin_nontemporal_load((const v4i*)(rec32 + (size_t)iA * 8));
            L1B = __builtin_nontemporal_load((const v4i*)(rec32 + (size_t)iB * 8));
            L2A = __builtin_nontemporal_load((const v2i*)(rec32 + (size_t)iA * 8 + 4));
            L2B = __builtin_nontemporal_load((const v2i*)(rec32 + (size_t)iB * 8 + 4));
            xpA = *(const v2i*)(xlh + (size_t)L1A.x * HC + 4 * cl);
            xpB = *(const v2i*)(xlh + (size_t)L1B.x * HC + 4 * cl);
        }
        edge_update_h(weA, weB, attA, attB, xr2a, xr2b, vA, c1A, c2A, cxA, denA, accA);
        edge_update_h(weA, weB, attA, attB, xr2a, xr2b, vB, c1B, c2B, cxB, denB, accB);
    }
#undef IDXA
#undef IDXB

    float den = denA + denB;
    float4 acc;
    acc.x = accA.x + accB.x;
    acc.y = accA.y + accB.y;
    acc.z = accA.z + accB.z;
    acc.w = accA.w + accB.w;

    // merge the 4 g-streams (lanes differing in bits 4,5) — plain sums
    den   += __shfl_xor(den, 16);   den   += __shfl_xor(den, 32);
    acc.x += __shfl_xor(acc.x, 16); acc.x += __shfl_xor(acc.x, 32);
    acc.y += __shfl_xor(acc.y, 16); acc.y += __shfl_xor(acc.y, 32);
    acc.z += __shfl_xor(acc.z, 16); acc.z += __shfl_xor(acc.z, 32);
    acc.w += __shfl_xor(acc.w, 16); acc.w += __shfl_xor(acc.w, 32);

    float4 b1v  = *(const float4*)(b1 + 4 * cl);
    float4 wl2v = *(const float4*)(Wl2 + 4 * cl);
    float4 wr2v = *(const float4*)(Wr2 + 4 * cl);
    float inv_den = 1.f / den;
    float4 o;
    o.x = acc.x * inv_den + b1v.x;
    o.y = acc.y * inv_den + b1v.y;
    o.z = acc.z * inv_den + b1v.z;
    o.w = acc.w * inv_den + b1v.w;
    o.x = o.x > 0.f ? o.x : __expf(o.x) - 1.f;   // ELU
    o.y = o.y > 0.f ? o.y : __expf(o.y) - 1.f;
    o.z = o.z > 0.f ? o.z : __expf(o.z) - 1.f;
    o.w = o.w > 0.f ? o.w : __expf(o.w) - 1.f;
    float sl = o.x*wl2v.x + o.y*wl2v.y + o.z*wl2v.z + o.w*wl2v.w;
    float sr = o.x*wr2v.x + o.y*wr2v.y + o.z*wr2v.z + o.w*wr2v.w;
#pragma unroll
    for (int off = 1; off <= 8; off <<= 1) {
        sl += __shfl_xor(sl, off);
        sr += __shfl_xor(sr, off);
    }
    if (lane == 0) {
        xl2[node] = sl + bl2[0];
        xr2[node] = sr + br2[0];
    }
}

// fused layer-2: 16 lanes per node (4 nodes/wave), no-max softmax.
__global__ __launch_bounds__(256) void gat2_kernel(
        const unsigned* __restrict__ row_start, const unsigned* __restrict__ deg,
        const int* __restrict__ rec32, const float* __restrict__ att2,
        const float* __restrict__ xl2, const float* __restrict__ xr2,
        const float* __restrict__ b2, float* __restrict__ out) {
    int wave = threadIdx.x >> 6;
    int lane = threadIdx.x & 63;
    int sub  = lane >> 4;                 // node within wave
    int l    = lane & 15;
    int node = (blockIdx.x * 4 + wave) * 4 + sub;   // grid 6250 * 16 = 100000 exact
    unsigned start = row_start[node];
    unsigned cnt   = deg[node] + 1u;
    float xrv = xr2[node];
    float a2  = att2[0];
    float den = 0.f, num = 0.f;
    for (unsigned idx = (unsigned)l; idx < cnt; idx += 16) {
        v2i r = __builtin_nontemporal_load((const v2i*)(rec32 + (size_t)(start + idx) * 8));
        float ee = __int_as_float(r.y);
        float xv = xl2[r.x];
        float v = xv + xrv + ee;
        v = fmaxf(v, NEG * v);
        float p = __expf(a2 * v);
        den += p;
        num += p * xv;
    }
#pragma unroll
    for (int off = 1; off <= 8; off <<= 1) {
        den += __shfl_xor(den, off);
        num += __shfl_xor(num, off);
    }
    if (l == 0) out[node] = num / den + b2[0];
}

extern "C" void kernel_launch(void* const* d_in, const int* in_sizes, int n_in,
                              void* d_out, int out_size, void* d_ws, size_t ws_size,
                              hipStream_t stream) {
    const float* x    = (const float*)d_in[0];
    const int*   ei   = (const int*)d_in[1];
    const float* ea   = (const float*)d_in[2];
    const float* Wl1  = (const float*)d_in[3];
    const float* bl1  = (const float*)d_in[4];
    const float* Wr1  = (const float*)d_in[5];
    const float* br1  = (const float*)d_in[6];
    const float* We1  = (const float*)d_in[7];
    const float* att1 = (const float*)d_in[8];
    const float* b1   = (const float*)d_in[9];
    const float* Wl2  = (const float*)d_in[10];
    const float* bl2  = (const float*)d_in[11];
    const float* Wr2  = (const float*)d_in[12];
    const float* br2  = (const float*)d_in[13];
    const float* We2  = (const float*)d_in[14];
    const float* att2 = (const float*)d_in[15];
    const float* b2   = (const float*)d_in[16];

    const int* src = ei;              // edge_index row 0
    const int* dst = ei + N_EDGES;    // edge_index row 1

    float* W = (float*)d_ws;
    size_t o = 0;
    float*    sum8      = W + o;               o += 8;
    float*    partials  = W + o;               o += MS_BLOCKS * 8;
    unsigned* deg       = (unsigned*)(W + o);  o += N_NODES;
    unsigned* local_inc = (unsigned*)(W + o);  o += N_NODES;
    unsigned* bsum      = (unsigned*)(W + o);  o += 128;
    unsigned* row_start = (unsigned*)(W + o);  o += N_NODES;
    unsigned* next      = (unsigned*)(W + o);  o += N_NODES;
    o = (o + 7) & ~(size_t)7;                  // 32B align
    int*      rec32     = (int*)(W + o);       o += (size_t)N_ITEMS * 8;      // 32B AoS
    __half*   xlh       = (__half*)(W + o);    o += (size_t)N_NODES * (HC/2); // fp16 xl
    __half*   xrh       = (__half*)(W + o);    o += (size_t)N_NODES * (HC/2); // fp16 xr
    float*    xl2       = W + o;               o += N_NODES;
    float*    xr2       = W + o;               o += N_NODES;

    hipMemsetAsync(deg, 0, (size_t)N_NODES * sizeof(unsigned), stream);
    mean_sum_kernel<<<MS_BLOCKS, 256, 0, stream>>>(ea, dst, partials, deg);
    scan1<<<SCAN_NB, SCAN_BS, 0, stream>>>(deg, local_inc, bsum, partials, sum8);
    scan23<<<(N_NODES + 255) / 256, 256, 0, stream>>>(local_inc, deg, bsum, row_start, next);
    scatter_kernel<<<(N_ITEMS + 255) / 256, 256, 0, stream>>>(
        src, dst, ea, sum8, We2, next, rec32);
    gemm1_kernel<<<N_NODES / 32, 256, 0, stream>>>(x, Wl1, bl1, Wr1, br1, xlh, xrh);
    gat1_kernel<<<(N_NODES + 3) / 4, 256, 0, stream>>>(
        row_start, deg, rec32, We1, att1, b1, xlh, xrh,
        Wl2, bl2, Wr2, br2, xl2, xr2);
    gat2_kernel<<<N_NODES / 16, 256, 0, stream>>>(
        row_start, deg, rec32, att2, xl2, xr2, b2, (float*)d_out);
}